// Round 2
// baseline (145.059 us; speedup 1.0000x reference)
//
#include <hip/hip_runtime.h>

#define N_   32
#define C_   3
#define T_   300
#define V_   25
#define OUT_ 96
#define VV   (V_*V_)   // 625
#define K12  12        // NUM_SCALES * C

// ---------------------------------------------------------------------------
// K1: per (n, t-chunk) block: build A = exp(-pdist^2), A^2, A^3 per t,
// accumulate over the chunk's 25 t's in LDS, atomicAdd into global S[n][3][625].
// ---------------------------------------------------------------------------
__global__ __launch_bounds__(256) void k_powsum(const float* __restrict__ xx,
                                                float* __restrict__ Ssum) {
    const int n     = blockIdx.x;
    const int chunk = blockIdx.y;   // 12 chunks x 25 t = 300
    const int tid   = threadIdx.x;

    __shared__ float xs[C_*V_];          // 75
    __shared__ float A[VV], A2[VV];      // 625 each
    __shared__ float acc1[VV], acc2[VV], acc3[VV];

    for (int i = tid; i < VV; i += 256) { acc1[i]=0.f; acc2[i]=0.f; acc3[i]=0.f; }
    __syncthreads();

    const float* xxn = xx + (size_t)n * C_*T_*V_;   // (C,T,V), M=1 is flat
    const int t0 = chunk * 25;

    for (int tt = 0; tt < 25; ++tt) {
        const int t = t0 + tt;
        if (tid < C_*V_) {
            const int c = tid / V_, v = tid % V_;
            xs[tid] = xxn[c*(T_*V_) + t*V_ + v];
        }
        __syncthreads();
        // A and acc1
        for (int i = tid; i < VV; i += 256) {
            const int v = i / V_, u = i % V_;
            const float d0 = xs[0*V_+v] - xs[0*V_+u];
            const float d1 = xs[1*V_+v] - xs[1*V_+u];
            const float d2 = xs[2*V_+v] - xs[2*V_+u];
            const float a = __expf(-(d0*d0 + d1*d1 + d2*d2));
            A[i] = a;
            acc1[i] += a;
        }
        __syncthreads();
        // A^2
        for (int i = tid; i < VV; i += 256) {
            const int v = i / V_, u = i % V_;
            float s = 0.f;
            #pragma unroll
            for (int w = 0; w < V_; ++w) s += A[v*V_+w] * A[w*V_+u];
            A2[i] = s;
            acc2[i] += s;
        }
        __syncthreads();
        // A^3 (accumulate directly)
        for (int i = tid; i < VV; i += 256) {
            const int v = i / V_, u = i % V_;
            float s = 0.f;
            #pragma unroll
            for (int w = 0; w < V_; ++w) s += A2[v*V_+w] * A[w*V_+u];
            acc3[i] += s;
        }
        __syncthreads();   // protect A/A2/xs before next t overwrites
    }

    float* Sn = Ssum + (size_t)n * 3 * VV;
    for (int i = tid; i < VV; i += 256) {
        atomicAdd(&Sn[i],        acc1[i]);
        atomicAdd(&Sn[VV + i],   acc2[i]);
        atomicAdd(&Sn[2*VV + i], acc3[i]);
    }
}

// ---------------------------------------------------------------------------
// K2: per (n, t-tile) block: agg[k][v] = sum_u S[n,s,v,u]*x[n,c,t,u]
// (s=0 -> 300*x), then out[n,o,t,v] = relu((sum_k W[o,k]*agg + b)*g/sqrt(1+eps)+beta)
// ---------------------------------------------------------------------------
__global__ __launch_bounds__(256) void k_out(const float* __restrict__ x,
                                             const float* __restrict__ Ssum,
                                             const float* __restrict__ W,
                                             const float* __restrict__ b,
                                             const float* __restrict__ gamma,
                                             const float* __restrict__ beta,
                                             float* __restrict__ out) {
    const int n    = blockIdx.x;
    const int tile = blockIdx.y;   // 30 tiles x 10 t = 300
    const int tid  = threadIdx.x;

    __shared__ float S_l[3*VV];       // 1875
    __shared__ float W_l[OUT_*K12];   // 1152
    __shared__ float scale[OUT_], off[OUT_];
    __shared__ float xsh[C_*V_];      // 75
    __shared__ float aggs[K12*V_];    // 300

    const float inv_bn = rsqrtf(1.0f + 1e-5f);
    for (int i = tid; i < 3*VV; i += 256) S_l[i] = Ssum[(size_t)n*3*VV + i];
    for (int i = tid; i < OUT_*K12; i += 256) W_l[i] = W[i];
    if (tid < OUT_) {
        const float sc = gamma[tid] * inv_bn;
        scale[tid] = sc;
        off[tid]   = b[tid]*sc + beta[tid];
    }
    __syncthreads();

    const float* xn = x   + (size_t)n * C_*T_*V_;
    float*       on = out + (size_t)n * OUT_*T_*V_;
    const int t0 = tile * 10;

    for (int tt = 0; tt < 10; ++tt) {
        const int t = t0 + tt;
        if (tid < C_*V_) xsh[tid] = xn[(tid/V_)*(T_*V_) + t*V_ + (tid%V_)];
        __syncthreads();

        // FIX(round1): K12*V_ = 300 > blockDim 256 — must be a strided loop,
        // the old `if (tid < 300)` left aggs[256..299] (s=3 rows) garbage.
        for (int i = tid; i < K12*V_; i += 256) {
            const int k = i / V_, v = i % V_;
            const int s = k / C_, c = k % C_;
            float val;
            if (s == 0) {
                val = (float)T_ * xsh[c*V_+v];
            } else {
                const float* Srow = &S_l[(s-1)*VV + v*V_];
                const float* xc   = &xsh[c*V_];
                float acc = 0.f;
                #pragma unroll
                for (int u = 0; u < V_; ++u) acc += Srow[u] * xc[u];
                val = acc;
            }
            aggs[i] = val;
        }
        __syncthreads();

        for (int e = tid; e < OUT_*V_; e += 256) {
            const int o = e / V_, v = e % V_;
            const float* wr = &W_l[o*K12];
            float acc = 0.f;
            #pragma unroll
            for (int k = 0; k < K12; ++k) acc += wr[k] * aggs[k*V_+v];
            float r = acc*scale[o] + off[o];
            on[o*(T_*V_) + t*V_ + v] = r > 0.f ? r : 0.f;
        }
        __syncthreads();
    }
}

extern "C" void kernel_launch(void* const* d_in, const int* in_sizes, int n_in,
                              void* d_out, int out_size, void* d_ws, size_t ws_size,
                              hipStream_t stream) {
    const float* x     = (const float*)d_in[0];
    const float* xx    = (const float*)d_in[1];
    const float* W     = (const float*)d_in[2];
    const float* b     = (const float*)d_in[3];
    const float* gamma = (const float*)d_in[4];
    const float* beta  = (const float*)d_in[5];
    float* out  = (float*)d_out;
    float* Ssum = (float*)d_ws;   // N * 3 * 625 floats = 240 KB

    hipMemsetAsync(Ssum, 0, (size_t)N_*3*VV*sizeof(float), stream);
    k_powsum<<<dim3(N_, 12), 256, 0, stream>>>(xx, Ssum);
    k_out  <<<dim3(N_, 30), 256, 0, stream>>>(x, Ssum, W, b, gamma, beta, out);
}

// Round 3
// 86.372 us; speedup vs baseline: 1.6795x; 1.6795x over previous
//
#include <hip/hip_runtime.h>

#define N_   32
#define C_   3
#define T_   300
#define V_   25
#define OUT_ 96
#define TT1  10          // t-tile per block
#define ROWP 28          // padded row length (multiple of 4 for float4)
#define ATS  (V_*ROWP)   // 700 floats per t-slice

// ---------------------------------------------------------------------------
// K1: block = (n, 10-t tile). Build all 10 A matrices in LDS, then A^2, A^3
// with 5x5-register-tiled symmetric row-dot matmuls, reduce over t, atomicAdd.
// Only 4 barriers per block.
// ---------------------------------------------------------------------------
__global__ __launch_bounds__(256) void k_powsum(const float* __restrict__ xx,
                                                float* __restrict__ Ssum) {
    const int n = blockIdx.x, chunk = blockIdx.y;   // 30 chunks x 10 t
    const int tid = threadIdx.x;

    __shared__ __align__(16) float xs[C_*TT1*ROWP];   // [c][t][28] = 840
    __shared__ __align__(16) float A [TT1*ATS];       // [t][v][28] = 7000
    __shared__ __align__(16) float A2[TT1*ATS];
    __shared__ __align__(16) float A3[TT1*ATS];

    const float* xxn = xx + (size_t)n * C_*T_*V_;
    const int t0 = chunk * TT1;

    // stage xs; pad columns: c==0 gets 1e18 so exp(-(x-1e18)^2)=exp(-1e36)=0,
    // making A's pad columns exactly 0 with no extra pass.
    for (int i = tid; i < C_*TT1*ROWP; i += 256) {
        const int c = i / (TT1*ROWP), r = i % (TT1*ROWP), t = r / ROWP, u = r % ROWP;
        xs[i] = (u < V_) ? xxn[c*(T_*V_) + (t0+t)*V_ + u]
                         : ((c == 0) ? 1e18f : 0.f);
    }
    __syncthreads();

    // build A: one (t, v-row) per thread, vectorized over u (incl. pad -> 0)
    if (tid < TT1*V_) {
        const int t = tid / V_, v = tid % V_;
        const float* x0 = &xs[0*(TT1*ROWP) + t*ROWP];
        const float* x1 = &xs[1*(TT1*ROWP) + t*ROWP];
        const float* x2 = &xs[2*(TT1*ROWP) + t*ROWP];
        const float xv0 = x0[v], xv1 = x1[v], xv2 = x2[v];
        float* Arow = &A[t*ATS + v*ROWP];
        #pragma unroll
        for (int u4 = 0; u4 < ROWP; u4 += 4) {
            const float4 q0 = *(const float4*)&x0[u4];
            const float4 q1 = *(const float4*)&x1[u4];
            const float4 q2 = *(const float4*)&x2[u4];
            float4 a;
            {   float d0=xv0-q0.x, d1=xv1-q1.x, d2=xv2-q2.x;
                a.x = __expf(-(d0*d0 + d1*d1 + d2*d2)); }
            {   float d0=xv0-q0.y, d1=xv1-q1.y, d2=xv2-q2.y;
                a.y = __expf(-(d0*d0 + d1*d1 + d2*d2)); }
            {   float d0=xv0-q0.z, d1=xv1-q1.z, d2=xv2-q2.z;
                a.z = __expf(-(d0*d0 + d1*d1 + d2*d2)); }
            {   float d0=xv0-q0.w, d1=xv1-q1.w, d2=xv2-q2.w;
                a.w = __expf(-(d0*d0 + d1*d1 + d2*d2)); }
            *(float4*)&Arow[u4] = a;
        }
    }
    __syncthreads();

    const int t  = tid / 25;
    const int tl = tid % 25;
    const int vt = (tl / 5) * 5, ut = (tl % 5) * 5;

    // A2[v,u] = dot(A_row_v, A_row_u)   (A symmetric; pads are 0)
    if (tid < TT1*V_) {
        float acc[5][5];
        #pragma unroll
        for (int a=0;a<5;a++)
            #pragma unroll
            for (int b2=0;b2<5;b2++) acc[a][b2]=0.f;
        const float* Ab = &A[t*ATS];
        #pragma unroll
        for (int w = 0; w < ROWP; w += 4) {
            float4 ar[5], au[5];
            #pragma unroll
            for (int a=0;a<5;a++) ar[a] = *(const float4*)&Ab[(vt+a)*ROWP + w];
            #pragma unroll
            for (int b2=0;b2<5;b2++) au[b2] = *(const float4*)&Ab[(ut+b2)*ROWP + w];
            #pragma unroll
            for (int a=0;a<5;a++)
                #pragma unroll
                for (int b2=0;b2<5;b2++)
                    acc[a][b2] += ar[a].x*au[b2].x + ar[a].y*au[b2].y
                                + ar[a].z*au[b2].z + ar[a].w*au[b2].w;
        }
        #pragma unroll
        for (int a=0;a<5;a++)
            #pragma unroll
            for (int b2=0;b2<5;b2++)
                A2[t*ATS + (vt+a)*ROWP + ut+b2] = acc[a][b2];
    }
    __syncthreads();

    // A3[v,u] = dot(A2_row_v, A_row_u)  (A pad=0 kills A2's unwritten pads)
    if (tid < TT1*V_) {
        float acc[5][5];
        #pragma unroll
        for (int a=0;a<5;a++)
            #pragma unroll
            for (int b2=0;b2<5;b2++) acc[a][b2]=0.f;
        const float* Ab  = &A[t*ATS];
        const float* A2b = &A2[t*ATS];
        #pragma unroll
        for (int w = 0; w < ROWP; w += 4) {
            float4 ar[5], au[5];
            #pragma unroll
            for (int a=0;a<5;a++) ar[a] = *(const float4*)&A2b[(vt+a)*ROWP + w];
            #pragma unroll
            for (int b2=0;b2<5;b2++) au[b2] = *(const float4*)&Ab[(ut+b2)*ROWP + w];
            #pragma unroll
            for (int a=0;a<5;a++)
                #pragma unroll
                for (int b2=0;b2<5;b2++)
                    acc[a][b2] += ar[a].x*au[b2].x + ar[a].y*au[b2].y
                                + ar[a].z*au[b2].z + ar[a].w*au[b2].w;
        }
        #pragma unroll
        for (int a=0;a<5;a++)
            #pragma unroll
            for (int b2=0;b2<5;b2++)
                A3[t*ATS + (vt+a)*ROWP + ut+b2] = acc[a][b2];
    }
    __syncthreads();

    // reduce over the 10 t's, then one atomicAdd per (matrix, element)
    float* Sn = Ssum + (size_t)n * 3*V_*V_;
    for (int e = tid; e < V_*V_; e += 256) {
        const int v = e / V_, u = e % V_;
        float s1=0.f, s2=0.f, s3=0.f;
        #pragma unroll
        for (int tq = 0; tq < TT1; ++tq) {
            const int o = tq*ATS + v*ROWP + u;
            s1 += A[o]; s2 += A2[o]; s3 += A3[o];
        }
        atomicAdd(&Sn[e],           s1);
        atomicAdd(&Sn[V_*V_ + e],   s2);
        atomicAdd(&Sn[2*V_*V_ + e], s3);
    }
}

// ---------------------------------------------------------------------------
// K2: block = (n, 10-t tile); 250 threads own one (tt,v) each, agg[12] in
// registers, epilogue loops o with uniform (scalar-load) W/b/gamma/beta and
// 1000B-contiguous stores per o. One barrier.
// ---------------------------------------------------------------------------
__global__ __launch_bounds__(256) void k_out(const float* __restrict__ x,
                                             const float* __restrict__ Ssum,
                                             const float* __restrict__ W,
                                             const float* __restrict__ b,
                                             const float* __restrict__ gamma,
                                             const float* __restrict__ beta,
                                             float* __restrict__ out) {
    const int n = blockIdx.x, tile = blockIdx.y;  // 30 tiles x 10 t
    const int tid = threadIdx.x;

    __shared__ __align__(16) float S_l[3*V_*ROWP];    // [s][v][28] = 2100
    __shared__ __align__(16) float xsh[TT1*C_*ROWP];  // [tt][c][28] = 840

    const float* xn = x + (size_t)n * C_*T_*V_;
    const int t0 = tile * TT1;

    for (int i = tid; i < 3*V_*ROWP; i += 256) {
        const int s = i/(V_*ROWP), r = i%(V_*ROWP), v = r/ROWP, u = r%ROWP;
        S_l[i] = (u < V_) ? Ssum[(size_t)n*3*V_*V_ + s*V_*V_ + v*V_ + u] : 0.f;
    }
    for (int i = tid; i < TT1*C_*ROWP; i += 256) {
        const int tt = i/(C_*ROWP), r = i%(C_*ROWP), c = r/ROWP, u = r%ROWP;
        xsh[i] = (u < V_) ? xn[c*(T_*V_) + (t0+tt)*V_ + u] : 0.f;
    }
    __syncthreads();

    if (tid < TT1*V_) {
        const int tt = tid / V_, iv = tid % V_;
        const float* xb = &xsh[tt*C_*ROWP];
        float agg[12];
        agg[0] = (float)T_ * xb[0*ROWP + iv];
        agg[1] = (float)T_ * xb[1*ROWP + iv];
        agg[2] = (float)T_ * xb[2*ROWP + iv];
        #pragma unroll
        for (int s = 1; s < 4; ++s) {
            float a0=0.f, a1=0.f, a2=0.f;
            const float* Srow = &S_l[(s-1)*V_*ROWP + iv*ROWP];
            #pragma unroll
            for (int u4 = 0; u4 < ROWP; u4 += 4) {
                const float4 sv = *(const float4*)&Srow[u4];
                const float4 q0 = *(const float4*)&xb[0*ROWP + u4];
                const float4 q1 = *(const float4*)&xb[1*ROWP + u4];
                const float4 q2 = *(const float4*)&xb[2*ROWP + u4];
                a0 += sv.x*q0.x + sv.y*q0.y + sv.z*q0.z + sv.w*q0.w;
                a1 += sv.x*q1.x + sv.y*q1.y + sv.z*q1.z + sv.w*q1.w;
                a2 += sv.x*q2.x + sv.y*q2.y + sv.z*q2.z + sv.w*q2.w;
            }
            agg[3*s+0]=a0; agg[3*s+1]=a1; agg[3*s+2]=a2;
        }

        const float inv_bn = rsqrtf(1.0f + 1e-5f);
        float* on = out + (size_t)n*(size_t)OUT_*T_*V_ + t0*V_ + tid;
        #pragma unroll 4
        for (int o = 0; o < OUT_; ++o) {
            const float sc = gamma[o] * inv_bn;
            const float of = b[o]*sc + beta[o];
            const float* wr = &W[o*12];
            float acc = 0.f;
            #pragma unroll
            for (int k = 0; k < 12; ++k) acc += wr[k] * agg[k];
            const float rl = fmaxf(acc*sc + of, 0.f);
            on[(size_t)o*(T_*V_)] = rl;
        }
    }
}

extern "C" void kernel_launch(void* const* d_in, const int* in_sizes, int n_in,
                              void* d_out, int out_size, void* d_ws, size_t ws_size,
                              hipStream_t stream) {
    const float* x     = (const float*)d_in[0];
    const float* xx    = (const float*)d_in[1];
    const float* W     = (const float*)d_in[2];
    const float* b     = (const float*)d_in[3];
    const float* gamma = (const float*)d_in[4];
    const float* beta  = (const float*)d_in[5];
    float* out  = (float*)d_out;
    float* Ssum = (float*)d_ws;   // N * 3 * 625 floats = 240 KB

    hipMemsetAsync(Ssum, 0, (size_t)N_*3*V_*V_*sizeof(float), stream);
    k_powsum<<<dim3(N_, T_/TT1), 256, 0, stream>>>(xx, Ssum);
    k_out  <<<dim3(N_, T_/TT1), 256, 0, stream>>>(x, Ssum, W, b, gamma, beta, out);
}

// Round 4
// 85.428 us; speedup vs baseline: 1.6980x; 1.0110x over previous
//
#include <hip/hip_runtime.h>

#define N_   32
#define C_   3
#define T_   300
#define V_   25
#define OUT_ 96
#define TT1  10          // t-tile per block
#define ROWP 28          // padded row length (multiple of 4 for float4)
#define ATS  (V_*ROWP)   // 700 floats per t-slice

// ---------------------------------------------------------------------------
// K0: zero the 240KB accumulator. hipMemsetAsync's fillBufferAligned ran at
// 0.4 GB/s (55us, 64% of total) — a custom float4 zero kernel is ~2us.
// ---------------------------------------------------------------------------
__global__ __launch_bounds__(256) void k_zero(float4* __restrict__ p) {
    const int i = blockIdx.x * 256 + threadIdx.x;
    if (i < N_*3*V_*V_/4) p[i] = make_float4(0.f, 0.f, 0.f, 0.f);
}

// ---------------------------------------------------------------------------
// K1: block = (n, 10-t tile). Build all 10 A matrices in LDS, then A^2, A^3
// with 5x5-register-tiled symmetric row-dot matmuls, reduce over t, atomicAdd.
// Only 4 barriers per block.
// ---------------------------------------------------------------------------
__global__ __launch_bounds__(256) void k_powsum(const float* __restrict__ xx,
                                                float* __restrict__ Ssum) {
    const int n = blockIdx.x, chunk = blockIdx.y;   // 30 chunks x 10 t
    const int tid = threadIdx.x;

    __shared__ __align__(16) float xs[C_*TT1*ROWP];   // [c][t][28] = 840
    __shared__ __align__(16) float A [TT1*ATS];       // [t][v][28] = 7000
    __shared__ __align__(16) float A2[TT1*ATS];
    __shared__ __align__(16) float A3[TT1*ATS];

    const float* xxn = xx + (size_t)n * C_*T_*V_;
    const int t0 = chunk * TT1;

    // stage xs; pad columns: c==0 gets 1e18 so exp(-(x-1e18)^2)=exp(-1e36)=0,
    // making A's pad columns exactly 0 with no extra pass.
    for (int i = tid; i < C_*TT1*ROWP; i += 256) {
        const int c = i / (TT1*ROWP), r = i % (TT1*ROWP), t = r / ROWP, u = r % ROWP;
        xs[i] = (u < V_) ? xxn[c*(T_*V_) + (t0+t)*V_ + u]
                         : ((c == 0) ? 1e18f : 0.f);
    }
    __syncthreads();

    // build A: one (t, v-row) per thread, vectorized over u (incl. pad -> 0)
    if (tid < TT1*V_) {
        const int t = tid / V_, v = tid % V_;
        const float* x0 = &xs[0*(TT1*ROWP) + t*ROWP];
        const float* x1 = &xs[1*(TT1*ROWP) + t*ROWP];
        const float* x2 = &xs[2*(TT1*ROWP) + t*ROWP];
        const float xv0 = x0[v], xv1 = x1[v], xv2 = x2[v];
        float* Arow = &A[t*ATS + v*ROWP];
        #pragma unroll
        for (int u4 = 0; u4 < ROWP; u4 += 4) {
            const float4 q0 = *(const float4*)&x0[u4];
            const float4 q1 = *(const float4*)&x1[u4];
            const float4 q2 = *(const float4*)&x2[u4];
            float4 a;
            {   float d0=xv0-q0.x, d1=xv1-q1.x, d2=xv2-q2.x;
                a.x = __expf(-(d0*d0 + d1*d1 + d2*d2)); }
            {   float d0=xv0-q0.y, d1=xv1-q1.y, d2=xv2-q2.y;
                a.y = __expf(-(d0*d0 + d1*d1 + d2*d2)); }
            {   float d0=xv0-q0.z, d1=xv1-q1.z, d2=xv2-q2.z;
                a.z = __expf(-(d0*d0 + d1*d1 + d2*d2)); }
            {   float d0=xv0-q0.w, d1=xv1-q1.w, d2=xv2-q2.w;
                a.w = __expf(-(d0*d0 + d1*d1 + d2*d2)); }
            *(float4*)&Arow[u4] = a;
        }
    }
    __syncthreads();

    const int t  = tid / 25;
    const int tl = tid % 25;
    const int vt = (tl / 5) * 5, ut = (tl % 5) * 5;

    // A2[v,u] = dot(A_row_v, A_row_u)   (A symmetric; pads are 0)
    if (tid < TT1*V_) {
        float acc[5][5];
        #pragma unroll
        for (int a=0;a<5;a++)
            #pragma unroll
            for (int b2=0;b2<5;b2++) acc[a][b2]=0.f;
        const float* Ab = &A[t*ATS];
        #pragma unroll
        for (int w = 0; w < ROWP; w += 4) {
            float4 ar[5], au[5];
            #pragma unroll
            for (int a=0;a<5;a++) ar[a] = *(const float4*)&Ab[(vt+a)*ROWP + w];
            #pragma unroll
            for (int b2=0;b2<5;b2++) au[b2] = *(const float4*)&Ab[(ut+b2)*ROWP + w];
            #pragma unroll
            for (int a=0;a<5;a++)
                #pragma unroll
                for (int b2=0;b2<5;b2++)
                    acc[a][b2] += ar[a].x*au[b2].x + ar[a].y*au[b2].y
                                + ar[a].z*au[b2].z + ar[a].w*au[b2].w;
        }
        #pragma unroll
        for (int a=0;a<5;a++)
            #pragma unroll
            for (int b2=0;b2<5;b2++)
                A2[t*ATS + (vt+a)*ROWP + ut+b2] = acc[a][b2];
    }
    __syncthreads();

    // A3[v,u] = dot(A2_row_v, A_row_u)  (A pad=0 kills A2's unwritten pads)
    if (tid < TT1*V_) {
        float acc[5][5];
        #pragma unroll
        for (int a=0;a<5;a++)
            #pragma unroll
            for (int b2=0;b2<5;b2++) acc[a][b2]=0.f;
        const float* Ab  = &A[t*ATS];
        const float* A2b = &A2[t*ATS];
        #pragma unroll
        for (int w = 0; w < ROWP; w += 4) {
            float4 ar[5], au[5];
            #pragma unroll
            for (int a=0;a<5;a++) ar[a] = *(const float4*)&A2b[(vt+a)*ROWP + w];
            #pragma unroll
            for (int b2=0;b2<5;b2++) au[b2] = *(const float4*)&Ab[(ut+b2)*ROWP + w];
            #pragma unroll
            for (int a=0;a<5;a++)
                #pragma unroll
                for (int b2=0;b2<5;b2++)
                    acc[a][b2] += ar[a].x*au[b2].x + ar[a].y*au[b2].y
                                + ar[a].z*au[b2].z + ar[a].w*au[b2].w;
        }
        #pragma unroll
        for (int a=0;a<5;a++)
            #pragma unroll
            for (int b2=0;b2<5;b2++)
                A3[t*ATS + (vt+a)*ROWP + ut+b2] = acc[a][b2];
    }
    __syncthreads();

    // reduce over the 10 t's, then one atomicAdd per (matrix, element)
    float* Sn = Ssum + (size_t)n * 3*V_*V_;
    for (int e = tid; e < V_*V_; e += 256) {
        const int v = e / V_, u = e % V_;
        float s1=0.f, s2=0.f, s3=0.f;
        #pragma unroll
        for (int tq = 0; tq < TT1; ++tq) {
            const int o = tq*ATS + v*ROWP + u;
            s1 += A[o]; s2 += A2[o]; s3 += A3[o];
        }
        atomicAdd(&Sn[e],           s1);
        atomicAdd(&Sn[V_*V_ + e],   s2);
        atomicAdd(&Sn[2*V_*V_ + e], s3);
    }
}

// ---------------------------------------------------------------------------
// K2: block = (n, 10-t tile); 250 threads own one (tt,v) each, agg[12] in
// registers, epilogue loops o with uniform (scalar-load) W/b/gamma/beta and
// 1000B-contiguous stores per o. One barrier.
// ---------------------------------------------------------------------------
__global__ __launch_bounds__(256) void k_out(const float* __restrict__ x,
                                             const float* __restrict__ Ssum,
                                             const float* __restrict__ W,
                                             const float* __restrict__ b,
                                             const float* __restrict__ gamma,
                                             const float* __restrict__ beta,
                                             float* __restrict__ out) {
    const int n = blockIdx.x, tile = blockIdx.y;  // 30 tiles x 10 t
    const int tid = threadIdx.x;

    __shared__ __align__(16) float S_l[3*V_*ROWP];    // [s][v][28] = 2100
    __shared__ __align__(16) float xsh[TT1*C_*ROWP];  // [tt][c][28] = 840

    const float* xn = x + (size_t)n * C_*T_*V_;
    const int t0 = tile * TT1;

    for (int i = tid; i < 3*V_*ROWP; i += 256) {
        const int s = i/(V_*ROWP), r = i%(V_*ROWP), v = r/ROWP, u = r%ROWP;
        S_l[i] = (u < V_) ? Ssum[(size_t)n*3*V_*V_ + s*V_*V_ + v*V_ + u] : 0.f;
    }
    for (int i = tid; i < TT1*C_*ROWP; i += 256) {
        const int tt = i/(C_*ROWP), r = i%(C_*ROWP), c = r/ROWP, u = r%ROWP;
        xsh[i] = (u < V_) ? xn[c*(T_*V_) + (t0+tt)*V_ + u] : 0.f;
    }
    __syncthreads();

    if (tid < TT1*V_) {
        const int tt = tid / V_, iv = tid % V_;
        const float* xb = &xsh[tt*C_*ROWP];
        float agg[12];
        agg[0] = (float)T_ * xb[0*ROWP + iv];
        agg[1] = (float)T_ * xb[1*ROWP + iv];
        agg[2] = (float)T_ * xb[2*ROWP + iv];
        #pragma unroll
        for (int s = 1; s < 4; ++s) {
            float a0=0.f, a1=0.f, a2=0.f;
            const float* Srow = &S_l[(s-1)*V_*ROWP + iv*ROWP];
            #pragma unroll
            for (int u4 = 0; u4 < ROWP; u4 += 4) {
                const float4 sv = *(const float4*)&Srow[u4];
                const float4 q0 = *(const float4*)&xb[0*ROWP + u4];
                const float4 q1 = *(const float4*)&xb[1*ROWP + u4];
                const float4 q2 = *(const float4*)&xb[2*ROWP + u4];
                a0 += sv.x*q0.x + sv.y*q0.y + sv.z*q0.z + sv.w*q0.w;
                a1 += sv.x*q1.x + sv.y*q1.y + sv.z*q1.z + sv.w*q1.w;
                a2 += sv.x*q2.x + sv.y*q2.y + sv.z*q2.z + sv.w*q2.w;
            }
            agg[3*s+0]=a0; agg[3*s+1]=a1; agg[3*s+2]=a2;
        }

        const float inv_bn = rsqrtf(1.0f + 1e-5f);
        float* on = out + (size_t)n*(size_t)OUT_*T_*V_ + t0*V_ + tid;
        #pragma unroll 4
        for (int o = 0; o < OUT_; ++o) {
            const float sc = gamma[o] * inv_bn;
            const float of = b[o]*sc + beta[o];
            const float* wr = &W[o*12];
            float acc = 0.f;
            #pragma unroll
            for (int k = 0; k < 12; ++k) acc += wr[k] * agg[k];
            const float rl = fmaxf(acc*sc + of, 0.f);
            on[(size_t)o*(T_*V_)] = rl;
        }
    }
}

extern "C" void kernel_launch(void* const* d_in, const int* in_sizes, int n_in,
                              void* d_out, int out_size, void* d_ws, size_t ws_size,
                              hipStream_t stream) {
    const float* x     = (const float*)d_in[0];
    const float* xx    = (const float*)d_in[1];
    const float* W     = (const float*)d_in[2];
    const float* b     = (const float*)d_in[3];
    const float* gamma = (const float*)d_in[4];
    const float* beta  = (const float*)d_in[5];
    float* out  = (float*)d_out;
    float* Ssum = (float*)d_ws;   // N * 3 * 625 floats = 240 KB

    k_zero <<<(N_*3*V_*V_/4 + 255)/256, 256, 0, stream>>>((float4*)Ssum);
    k_powsum<<<dim3(N_, T_/TT1), 256, 0, stream>>>(xx, Ssum);
    k_out  <<<dim3(N_, T_/TT1), 256, 0, stream>>>(x, Ssum, W, b, gamma, beta, out);
}

// Round 5
// 83.170 us; speedup vs baseline: 1.7441x; 1.0272x over previous
//
#include <hip/hip_runtime.h>

#define N_   32
#define C_   3
#define T_   300
#define V_   25
#define OUT_ 96
#define ROWP 28              // padded row (float4-aligned)
#define ATS  (V_*ROWP)       // 700 floats per t-slice
#define TTP  5               // t's per k_powsum block
#define NCH  (T_/TTP)        // 60 chunks per n
#define TT2  10              // t's per k_out block
#define SEL  (3*V_*V_)       // 1875 floats per (n or partial) sum record

// ---------------------------------------------------------------------------
// K1: block = (n, 5-t chunk), 128 threads, LDS = A + A2 only (29.7 KB ->
// 5 blocks/CU). A,A2,A3 are symmetric: compute 15 upper 5x5 tiles per t,
// mirror-write. A3 lives in registers, then reuses A's LDS after A's t-sum
// is flushed. Block writes 1875-float partial sums (no atomics).
// ---------------------------------------------------------------------------
__global__ __launch_bounds__(128) void k_powsum(const float* __restrict__ xx,
                                                float* __restrict__ partial) {
    const int n = blockIdx.x, chunk = blockIdx.y;
    const int tid = threadIdx.x;

    __shared__ __align__(16) float xs[C_*TTP*ROWP];  // 420
    __shared__ __align__(16) float A [TTP*ATS];      // 3500
    __shared__ __align__(16) float A2[TTP*ATS];      // 3500

    const float* xxn = xx + (size_t)n * C_*T_*V_;
    const int t0 = chunk * TTP;

    // stage xs; pad cols: c==0 gets 1e18 so exp(-(1e18)^2) == 0 -> A pads = 0
    for (int i = tid; i < C_*TTP*ROWP; i += 128) {
        const int c = i/(TTP*ROWP), r = i%(TTP*ROWP), t = r/ROWP, u = r%ROWP;
        xs[i] = (u < V_) ? xxn[c*(T_*V_) + (t0+t)*V_ + u] : ((c==0)?1e18f:0.f);
    }
    // zero A2 pad columns (A2 tiles only write cols 0..24)
    if (tid < TTP*V_) {
        float* p = &A2[(tid/V_)*ATS + (tid%V_)*ROWP];
        p[25]=0.f; p[26]=0.f; p[27]=0.f;
    }
    __syncthreads();

    // build A: one (slot, v-row) per thread, vectorized over u (pads -> 0)
    if (tid < TTP*V_) {
        const int slot = tid/V_, v = tid%V_;
        const float* x0 = &xs[0*(TTP*ROWP) + slot*ROWP];
        const float* x1 = &xs[1*(TTP*ROWP) + slot*ROWP];
        const float* x2 = &xs[2*(TTP*ROWP) + slot*ROWP];
        const float xv0 = x0[v], xv1 = x1[v], xv2 = x2[v];
        float* Arow = &A[slot*ATS + v*ROWP];
        #pragma unroll
        for (int u4 = 0; u4 < ROWP; u4 += 4) {
            const float4 q0 = *(const float4*)&x0[u4];
            const float4 q1 = *(const float4*)&x1[u4];
            const float4 q2 = *(const float4*)&x2[u4];
            float4 a;
            {   float d0=xv0-q0.x, d1=xv1-q1.x, d2=xv2-q2.x;
                a.x = __expf(-(d0*d0 + d1*d1 + d2*d2)); }
            {   float d0=xv0-q0.y, d1=xv1-q1.y, d2=xv2-q2.y;
                a.y = __expf(-(d0*d0 + d1*d1 + d2*d2)); }
            {   float d0=xv0-q0.z, d1=xv1-q1.z, d2=xv2-q2.z;
                a.z = __expf(-(d0*d0 + d1*d1 + d2*d2)); }
            {   float d0=xv0-q0.w, d1=xv1-q1.w, d2=xv2-q2.w;
                a.w = __expf(-(d0*d0 + d1*d1 + d2*d2)); }
            *(float4*)&Arow[u4] = a;
        }
    }
    __syncthreads();

    // symmetric tile assignment: 15 upper tiles (i<=j) x 5 slots = 75 threads
    const bool act = (tid < TTP*15);
    const int slot = tid / 15;
    int ti = 0, tj = 0;
    {
        int r = tid % 15;
        #pragma unroll
        for (int i = 0; i < 5; ++i) {
            const int cnt = 5 - i;
            if (r < cnt) { ti = i; tj = i + r; break; }
            r -= cnt;
        }
    }
    const int vt = ti*5, ut = tj*5;

    // A2 tile = dot(A_row_v, A_row_u) (A symmetric, pads 0); mirror-write
    if (act) {
        float acc[5][5];
        #pragma unroll
        for (int a=0;a<5;a++)
            #pragma unroll
            for (int b2=0;b2<5;b2++) acc[a][b2]=0.f;
        const float* Ab = &A[slot*ATS];
        #pragma unroll
        for (int w = 0; w < ROWP; w += 4) {
            float4 ar[5], au[5];
            #pragma unroll
            for (int a=0;a<5;a++) ar[a] = *(const float4*)&Ab[(vt+a)*ROWP + w];
            #pragma unroll
            for (int b2=0;b2<5;b2++) au[b2] = *(const float4*)&Ab[(ut+b2)*ROWP + w];
            #pragma unroll
            for (int a=0;a<5;a++)
                #pragma unroll
                for (int b2=0;b2<5;b2++)
                    acc[a][b2] += ar[a].x*au[b2].x + ar[a].y*au[b2].y
                                + ar[a].z*au[b2].z + ar[a].w*au[b2].w;
        }
        float* A2b = &A2[slot*ATS];
        #pragma unroll
        for (int a=0;a<5;a++)
            #pragma unroll
            for (int b2=0;b2<5;b2++) {
                A2b[(vt+a)*ROWP + ut+b2] = acc[a][b2];
                A2b[(ut+b2)*ROWP + vt+a] = acc[a][b2];
            }
    }
    __syncthreads();

    // A3 tile in REGISTERS = dot(A2_row_v, A_row_u); A2 pads are 0
    float acc3[5][5];
    if (act) {
        #pragma unroll
        for (int a=0;a<5;a++)
            #pragma unroll
            for (int b2=0;b2<5;b2++) acc3[a][b2]=0.f;
        const float* Ab  = &A[slot*ATS];
        const float* A2b = &A2[slot*ATS];
        #pragma unroll
        for (int w = 0; w < ROWP; w += 4) {
            float4 ar[5], au[5];
            #pragma unroll
            for (int a=0;a<5;a++) ar[a] = *(const float4*)&A2b[(vt+a)*ROWP + w];
            #pragma unroll
            for (int b2=0;b2<5;b2++) au[b2] = *(const float4*)&Ab[(ut+b2)*ROWP + w];
            #pragma unroll
            for (int a=0;a<5;a++)
                #pragma unroll
                for (int b2=0;b2<5;b2++)
                    acc3[a][b2] += ar[a].x*au[b2].x + ar[a].y*au[b2].y
                                 + ar[a].z*au[b2].z + ar[a].w*au[b2].w;
        }
    }

    // t-sum A and A2 straight from LDS -> partial (read-only, no barrier vs acc3)
    float* pb = partial + ((size_t)n*NCH + chunk) * SEL;
    for (int e = tid; e < V_*V_; e += 128) {
        const int v = e/V_, u = e%V_;
        float s1=0.f, s2=0.f;
        #pragma unroll
        for (int sl = 0; sl < TTP; ++sl) {
            s1 += A [sl*ATS + v*ROWP + u];
            s2 += A2[sl*ATS + v*ROWP + u];
        }
        pb[e]         = s1;
        pb[V_*V_ + e] = s2;
    }
    __syncthreads();   // A's t-sum flushed; safe to overwrite A with A3

    if (act) {
        float* Ar = &A[slot*ATS];
        #pragma unroll
        for (int a=0;a<5;a++)
            #pragma unroll
            for (int b2=0;b2<5;b2++) {
                Ar[(vt+a)*ROWP + ut+b2] = acc3[a][b2];
                Ar[(ut+b2)*ROWP + vt+a] = acc3[a][b2];
            }
    }
    __syncthreads();

    for (int e = tid; e < V_*V_; e += 128) {
        const int v = e/V_, u = e%V_;
        float s3=0.f;
        #pragma unroll
        for (int sl = 0; sl < TTP; ++sl) s3 += A[sl*ATS + v*ROWP + u];
        pb[2*V_*V_ + e] = s3;
    }
}

// ---------------------------------------------------------------------------
// K1b: Ssum[n][j] = sum over 60 chunks of partial[n][c][j]. Deterministic.
// ---------------------------------------------------------------------------
__global__ __launch_bounds__(256) void k_reduce(const float* __restrict__ partial,
                                                float* __restrict__ Ssum) {
    const int g = blockIdx.x*256 + threadIdx.x;
    if (g >= N_*SEL) return;
    const int n = g / SEL, j = g % SEL;
    const float* p = partial + (size_t)n*NCH*SEL + j;
    float s = 0.f;
    #pragma unroll 4
    for (int c = 0; c < NCH; ++c) s += p[(size_t)c*SEL];
    Ssum[g] = s;
}

// ---------------------------------------------------------------------------
// K2: block = (n, 10-t tile); 250 threads own one (tt,v), agg[12] in regs,
// epilogue loops o over LDS-staged W/scale/off, 1000B-contiguous stores per o.
// ---------------------------------------------------------------------------
__global__ __launch_bounds__(256) void k_out(const float* __restrict__ x,
                                             const float* __restrict__ Ssum,
                                             const float* __restrict__ W,
                                             const float* __restrict__ b,
                                             const float* __restrict__ gamma,
                                             const float* __restrict__ beta,
                                             float* __restrict__ out) {
    const int n = blockIdx.x, tile = blockIdx.y;  // 30 tiles x 10 t
    const int tid = threadIdx.x;

    __shared__ __align__(16) float S_l[3*V_*ROWP];    // 2100
    __shared__ __align__(16) float xsh[TT2*C_*ROWP];  // 840
    __shared__ __align__(16) float Wl[OUT_*12];       // 1152
    __shared__ float scl[OUT_], off[OUT_];

    const float* xn = x + (size_t)n * C_*T_*V_;
    const int t0 = tile * TT2;
    const float inv_bn = rsqrtf(1.0f + 1e-5f);

    for (int i = tid; i < 3*V_*ROWP; i += 256) {
        const int s = i/(V_*ROWP), r = i%(V_*ROWP), v = r/ROWP, u = r%ROWP;
        S_l[i] = (u < V_) ? Ssum[(size_t)n*SEL + s*V_*V_ + v*V_ + u] : 0.f;
    }
    for (int i = tid; i < TT2*C_*ROWP; i += 256) {
        const int tt = i/(C_*ROWP), r = i%(C_*ROWP), c = r/ROWP, u = r%ROWP;
        xsh[i] = (u < V_) ? xn[c*(T_*V_) + (t0+tt)*V_ + u] : 0.f;
    }
    for (int i = tid; i < OUT_*12; i += 256) Wl[i] = W[i];
    if (tid < OUT_) {
        const float sc = gamma[tid] * inv_bn;
        scl[tid] = sc;
        off[tid] = b[tid]*sc + beta[tid];
    }
    __syncthreads();

    if (tid < TT2*V_) {
        const int tt = tid / V_, iv = tid % V_;
        const float* xb = &xsh[tt*C_*ROWP];
        float agg[12];
        agg[0] = (float)T_ * xb[0*ROWP + iv];
        agg[1] = (float)T_ * xb[1*ROWP + iv];
        agg[2] = (float)T_ * xb[2*ROWP + iv];
        #pragma unroll
        for (int s = 1; s < 4; ++s) {
            float a0=0.f, a1=0.f, a2=0.f;
            const float* Srow = &S_l[(s-1)*V_*ROWP + iv*ROWP];
            #pragma unroll
            for (int u4 = 0; u4 < ROWP; u4 += 4) {
                const float4 sv = *(const float4*)&Srow[u4];
                const float4 q0 = *(const float4*)&xb[0*ROWP + u4];
                const float4 q1 = *(const float4*)&xb[1*ROWP + u4];
                const float4 q2 = *(const float4*)&xb[2*ROWP + u4];
                a0 += sv.x*q0.x + sv.y*q0.y + sv.z*q0.z + sv.w*q0.w;
                a1 += sv.x*q1.x + sv.y*q1.y + sv.z*q1.z + sv.w*q1.w;
                a2 += sv.x*q2.x + sv.y*q2.y + sv.z*q2.z + sv.w*q2.w;
            }
            agg[3*s+0]=a0; agg[3*s+1]=a1; agg[3*s+2]=a2;
        }

        float* on = out + (size_t)n*(size_t)OUT_*T_*V_ + t0*V_ + tid;
        #pragma unroll 4
        for (int o = 0; o < OUT_; ++o) {
            const float4 w0 = *(const float4*)&Wl[o*12];
            const float4 w1 = *(const float4*)&Wl[o*12+4];
            const float4 w2 = *(const float4*)&Wl[o*12+8];
            float acc = w0.x*agg[0] + w0.y*agg[1] + w0.z*agg[2] + w0.w*agg[3]
                      + w1.x*agg[4] + w1.y*agg[5] + w1.z*agg[6] + w1.w*agg[7]
                      + w2.x*agg[8] + w2.y*agg[9] + w2.z*agg[10]+ w2.w*agg[11];
            const float rl = fmaxf(acc*scl[o] + off[o], 0.f);
            on[(size_t)o*(T_*V_)] = rl;
        }
    }
}

extern "C" void kernel_launch(void* const* d_in, const int* in_sizes, int n_in,
                              void* d_out, int out_size, void* d_ws, size_t ws_size,
                              hipStream_t stream) {
    const float* x     = (const float*)d_in[0];
    const float* xx    = (const float*)d_in[1];
    const float* W     = (const float*)d_in[2];
    const float* b     = (const float*)d_in[3];
    const float* gamma = (const float*)d_in[4];
    const float* beta  = (const float*)d_in[5];
    float* out  = (float*)d_out;

    float* Ssum    = (float*)d_ws;                 // 32*1875 floats = 240 KB
    float* partial = (float*)d_ws + (size_t)N_*SEL; // 1920*1875 floats = 14.4 MB

    k_powsum<<<dim3(N_, NCH), 128, 0, stream>>>(xx, partial);
    k_reduce<<<(N_*SEL + 255)/256, 256, 0, stream>>>(partial, Ssum);
    k_out   <<<dim3(N_, T_/TT2), 256, 0, stream>>>(x, Ssum, W, b, gamma, beta, out);
}